// Round 3
// baseline (280.655 us; speedup 1.0000x reference)
//
#include <hip/hip_runtime.h>
#include <math.h>

#define L_ 200

__device__ __forceinline__ unsigned f2bf_pair(float a, float b) {
  union { float f; unsigned u; } ca, cb;
  ca.f = a; cb.f = b;
  unsigned ra = (ca.u + 0x7FFFu + ((ca.u >> 16) & 1u)) >> 16;
  unsigned rb = (cb.u + 0x7FFFu + ((cb.u >> 16) & 1u)) >> 16;
  return (ra & 0xFFFFu) | ((rb & 0xFFFFu) << 16);
}

__device__ __forceinline__ float bf_lo(unsigned u) {
  union { unsigned u; float f; } c; c.u = u << 16; return c.f;
}
__device__ __forceinline__ float bf_hi(unsigned u) {
  union { unsigned u; float f; } c; c.u = u & 0xFFFF0000u; return c.f;
}

// ---------------- 1) emb fp32 -> bf16 (RNE), + W1 transpose-pack, + zero accumulators ----------------
__global__ __launch_bounds__(256) void convert_pack_kernel(
    const float* __restrict__ emb, uint2* __restrict__ embbf,
    const float* __restrict__ W1, float* __restrict__ W1p,
    float* __restrict__ ssum, float* __restrict__ ssq, float* __restrict__ out) {
  const int tid = threadIdx.x;
  if (blockIdx.x < 64) {
    float4 v = ((const float4*)W1)[tid * 64 + blockIdx.x];
    ((float4*)W1p)[blockIdx.x * 256 + tid] = v;
  } else if (blockIdx.x == 64) {
    ssum[tid] = 0.f;
    ssq[tid] = 0.f;
    if (tid == 0) out[0] = 0.f;
  }
  const float4* e4 = (const float4*)emb;
  const unsigned N4 = 100000u * 64u;   // 6,400,000 float4s
  for (unsigned i = blockIdx.x * 256 + tid; i < N4; i += 2048u * 256u) {
    float4 v = e4[i];
    uint2 o;
    o.x = f2bf_pair(v.x, v.y);
    o.y = f2bf_pair(v.z, v.w);
    embbf[i] = o;
  }
}

// ---------------- 2) pooling: 2 waves per row, bf16 gather (512B/row) ----------------
__global__ __launch_bounds__(256) void pool_kernel(
    const int* __restrict__ tokens, const int* __restrict__ lengths,
    const uint2* __restrict__ embbf, float* __restrict__ pooled) {
  const int tid = threadIdx.x;
  const int wv = tid >> 6, lane = tid & 63;
  const int row = blockIdx.x * 2 + (wv >> 1);
  const int half = wv & 1;
  const int len = lengths[row];
  const int* trow = tokens + row * L_;
  float4 a0 = make_float4(0.f, 0.f, 0.f, 0.f);
  float4 a1 = a0, a2 = a0, a3 = a0;
  for (int l0 = half * 64; l0 < len; l0 += 128) {
    int nt = len - l0; nt = nt > 64 ? 64 : nt;
    int tk = (lane < nt) ? trow[l0 + lane] : 0;   // coalesced token load
    int j = 0;
    for (; j + 4 <= nt; j += 4) {
      int t0 = __shfl(tk, j);
      int t1 = __shfl(tk, j + 1);
      int t2 = __shfl(tk, j + 2);
      int t3 = __shfl(tk, j + 3);
      uint2 v0 = embbf[(size_t)t0 * 64 + lane];
      uint2 v1 = embbf[(size_t)t1 * 64 + lane];
      uint2 v2 = embbf[(size_t)t2 * 64 + lane];
      uint2 v3 = embbf[(size_t)t3 * 64 + lane];
      a0.x += bf_lo(v0.x); a0.y += bf_hi(v0.x); a0.z += bf_lo(v0.y); a0.w += bf_hi(v0.y);
      a1.x += bf_lo(v1.x); a1.y += bf_hi(v1.x); a1.z += bf_lo(v1.y); a1.w += bf_hi(v1.y);
      a2.x += bf_lo(v2.x); a2.y += bf_hi(v2.x); a2.z += bf_lo(v2.y); a2.w += bf_hi(v2.y);
      a3.x += bf_lo(v3.x); a3.y += bf_hi(v3.x); a3.z += bf_lo(v3.y); a3.w += bf_hi(v3.y);
    }
    for (; j < nt; j++) {
      int t0 = __shfl(tk, j);
      uint2 v0 = embbf[(size_t)t0 * 64 + lane];
      a0.x += bf_lo(v0.x); a0.y += bf_hi(v0.x); a0.z += bf_lo(v0.y); a0.w += bf_hi(v0.y);
    }
  }
  float4 r;
  r.x = a0.x + a1.x + a2.x + a3.x;
  r.y = a0.y + a1.y + a2.y + a3.y;
  r.z = a0.z + a1.z + a2.z + a3.z;
  r.w = a0.w + a1.w + a2.w + a3.w;
  __shared__ float4 part[2][64];
  if (half) part[wv >> 1][lane] = r;
  __syncthreads();
  if (!half) {
    float4 o = part[wv >> 1][lane];
    const float inv = 1.0f / (float)len;
    r.x = (r.x + o.x) * inv;
    r.y = (r.y + o.y) * inv;
    r.z = (r.z + o.z) * inv;
    r.w = (r.w + o.w) * inv;
    ((float4*)pooled)[(size_t)row * 64 + lane] = r;
  }
}

// ---------------- 3) z = pooled @ W1^T + b1, BN stats accumulated via atomics ----------------
__global__ __launch_bounds__(256) void gemm_stats_kernel(
    const float* __restrict__ pooled, const float* __restrict__ W1p,
    const float* __restrict__ b1, float* __restrict__ z,
    float* __restrict__ ssum, float* __restrict__ ssq) {
  __shared__ float4 SH[1024];   // 16 KB: pooled tile during loop, stats after
  const int tid = threadIdx.x;
  const int b0 = blockIdx.x * 16;
  const float4* pooled4 = (const float4*)pooled;
#pragma unroll
  for (int i = 0; i < 4; i++)
    SH[tid + i * 256] = pooled4[(size_t)b0 * 64 + tid + i * 256];
  __syncthreads();
  const int wv = tid >> 6, lane = tid & 63;
  const int r0 = wv * 4;
  float4 bb = ((const float4*)b1)[lane];
  float acc[4][4];
#pragma unroll
  for (int r = 0; r < 4; r++) {
    acc[r][0] = bb.x; acc[r][1] = bb.y; acc[r][2] = bb.z; acc[r][3] = bb.w;
  }
  const float4* w4 = (const float4*)W1p;
  for (int kb = 0; kb < 64; kb++) {
    float4 wk0 = w4[kb * 256 + lane * 4 + 0];
    float4 wk1 = w4[kb * 256 + lane * 4 + 1];
    float4 wk2 = w4[kb * 256 + lane * 4 + 2];
    float4 wk3 = w4[kb * 256 + lane * 4 + 3];
#pragma unroll
    for (int r = 0; r < 4; r++) {
      float4 p = SH[(r0 + r) * 64 + kb];   // wave-uniform -> LDS broadcast
      acc[r][0] += p.x * wk0.x + p.y * wk0.y + p.z * wk0.z + p.w * wk0.w;
      acc[r][1] += p.x * wk1.x + p.y * wk1.y + p.z * wk1.z + p.w * wk1.w;
      acc[r][2] += p.x * wk2.x + p.y * wk2.y + p.z * wk2.z + p.w * wk2.w;
      acc[r][3] += p.x * wk3.x + p.y * wk3.y + p.z * wk3.z + p.w * wk3.w;
    }
  }
  float4* z4 = (float4*)z;
  float4 s = make_float4(0.f, 0.f, 0.f, 0.f), q = s;
#pragma unroll
  for (int r = 0; r < 4; r++) {
    float4 o = make_float4(acc[r][0], acc[r][1], acc[r][2], acc[r][3]);
    z4[(size_t)(b0 + r0 + r) * 64 + lane] = o;
    s.x += o.x; s.y += o.y; s.z += o.z; s.w += o.w;
    q.x += o.x * o.x; q.y += o.y * o.y; q.z += o.z * o.z; q.w += o.w * o.w;
  }
  __syncthreads();   // done reading pooled tile; reuse SH for stats
  SH[wv * 64 + lane] = s;
  SH[256 + wv * 64 + lane] = q;
  __syncthreads();
  if (tid < 64) {
    float4 S = make_float4(0.f, 0.f, 0.f, 0.f), Q = S;
#pragma unroll
    for (int w = 0; w < 4; w++) {
      float4 a = SH[w * 64 + tid];
      float4 b = SH[256 + w * 64 + tid];
      S.x += a.x; S.y += a.y; S.z += a.z; S.w += a.w;
      Q.x += b.x; Q.y += b.y; Q.z += b.z; Q.w += b.w;
    }
    atomicAdd(&ssum[4 * tid + 0], S.x);
    atomicAdd(&ssum[4 * tid + 1], S.y);
    atomicAdd(&ssum[4 * tid + 2], S.z);
    atomicAdd(&ssum[4 * tid + 3], S.w);
    atomicAdd(&ssq[4 * tid + 0], Q.x);
    atomicAdd(&ssq[4 * tid + 1], Q.y);
    atomicAdd(&ssq[4 * tid + 2], Q.z);
    atomicAdd(&ssq[4 * tid + 3], Q.w);
  }
}

// ---------------- 4) BN finalize + apply + ReLU + dot head + BCE + loss atomic ----------------
__global__ __launch_bounds__(256) void head_loss_kernel(
    const float* __restrict__ z, const float* __restrict__ ssum,
    const float* __restrict__ ssq, const float* __restrict__ gamma,
    const float* __restrict__ beta, const float* __restrict__ w2,
    const float* __restrict__ b2, const float* __restrict__ t,
    float* __restrict__ out) {
  const int tid = threadIdx.x;
  const int wv = tid >> 6, lane = tid & 63;
  const int b = blockIdx.x * 4 + wv;
  float4 s4 = ((const float4*)ssum)[lane];
  float4 q4 = ((const float4*)ssq)[lane];
  float4 g4 = ((const float4*)gamma)[lane];
  float4 be4 = ((const float4*)beta)[lane];
  float4 w24 = ((const float4*)w2)[lane];
  const float invB = 1.0f / 4096.0f;
  float4 A4, C4;
  {
    float m = s4.x * invB, v = q4.x * invB - m * m;
    float rs = rsqrtf(v + 1e-5f); A4.x = g4.x * rs; C4.x = be4.x - m * A4.x;
  }
  {
    float m = s4.y * invB, v = q4.y * invB - m * m;
    float rs = rsqrtf(v + 1e-5f); A4.y = g4.y * rs; C4.y = be4.y - m * A4.y;
  }
  {
    float m = s4.z * invB, v = q4.z * invB - m * m;
    float rs = rsqrtf(v + 1e-5f); A4.z = g4.z * rs; C4.z = be4.z - m * A4.z;
  }
  {
    float m = s4.w * invB, v = q4.w * invB - m * m;
    float rs = rsqrtf(v + 1e-5f); A4.w = g4.w * rs; C4.w = be4.w - m * A4.w;
  }
  float4 zv = ((const float4*)z)[(size_t)b * 64 + lane];
  float h0 = fmaxf(A4.x * zv.x + C4.x, 0.f);
  float h1 = fmaxf(A4.y * zv.y + C4.y, 0.f);
  float h2 = fmaxf(A4.z * zv.z + C4.z, 0.f);
  float h3 = fmaxf(A4.w * zv.w + C4.w, 0.f);
  float part = h0 * w24.x + h1 * w24.y + h2 * w24.z + h3 * w24.w;
#pragma unroll
  for (int off = 32; off > 0; off >>= 1) part += __shfl_down(part, off);
  __shared__ float red[4];
  if (lane == 0) {
    float logit = part + b2[0];
    out[1 + b] = logit;
    float tb = t[b];
    red[wv] = fmaxf(logit, 0.f) - logit * tb + log1pf(expf(-fabsf(logit)));
  }
  __syncthreads();
  if (tid == 0)
    atomicAdd(out, (red[0] + red[1] + red[2] + red[3]) * (1.0f / 4096.0f));
}

extern "C" void kernel_launch(void* const* d_in, const int* in_sizes, int n_in,
                              void* d_out, int out_size, void* d_ws, size_t ws_size,
                              hipStream_t stream) {
  const int* tokens = (const int*)d_in[0];
  const int* lengths = (const int*)d_in[1];
  const float* t = (const float*)d_in[2];
  const float* emb = (const float*)d_in[3];
  const float* W1 = (const float*)d_in[4];
  const float* b1 = (const float*)d_in[5];
  const float* gamma = (const float*)d_in[6];
  const float* beta = (const float*)d_in[7];
  const float* w2 = (const float*)d_in[8];
  const float* b2 = (const float*)d_in[9];
  float* out = (float*)d_out;

  float* wsf = (float*)d_ws;
  uint2* embbf = (uint2*)d_ws;          // 100000*256 bf16 = 51,200,000 B (= 12,800,000 float units)
  float* pooled = wsf + 12800000;       // 1,048,576 floats
  float* z = wsf + 13848576;            // 1,048,576
  float* W1p = wsf + 14897152;          // 65,536
  float* ssum = wsf + 14962688;         // 256
  float* ssq = wsf + 14962944;          // 256
  // total ~59.9 MB of d_ws

  convert_pack_kernel<<<2048, 256, 0, stream>>>(emb, embbf, W1, W1p, ssum, ssq, out);
  pool_kernel<<<2048, 256, 0, stream>>>(tokens, lengths, embbf, pooled);
  gemm_stats_kernel<<<256, 256, 0, stream>>>(pooled, W1p, b1, z, ssum, ssq);
  head_loss_kernel<<<1024, 256, 0, stream>>>(z, ssum, ssq, gamma, beta, w2, b2, t, out);
}

// Round 4
// 271.506 us; speedup vs baseline: 1.0337x; 1.0337x over previous
//
#include <hip/hip_runtime.h>
#include <math.h>

#define L_ 200

// ---------------- 1) pooling (fp32): 2 waves per row, 8 rows in flight; + W1 pack + zero accs ----------------
__global__ __launch_bounds__(256) void pool_pack_kernel(
    const int* __restrict__ tokens, const int* __restrict__ lengths,
    const float* __restrict__ emb, float* __restrict__ pooled,
    const float* __restrict__ W1, float* __restrict__ W1p,
    float* __restrict__ ssum, float* __restrict__ ssq, float* __restrict__ out) {
  const int tid = threadIdx.x;
  // piggyback: blocks 0..63 transpose-pack W1; block 64 zeroes accumulators + loss slot
  if (blockIdx.x < 64) {
    float4 v = ((const float4*)W1)[tid * 64 + blockIdx.x];
    ((float4*)W1p)[blockIdx.x * 256 + tid] = v;
  } else if (blockIdx.x == 64) {
    ssum[tid] = 0.f;
    ssq[tid] = 0.f;
    if (tid == 0) out[0] = 0.f;
  }
  const int wv = tid >> 6, lane = tid & 63;
  const int row = blockIdx.x * 2 + (wv >> 1);
  const int half = wv & 1;
  const int len = lengths[row];
  const int* trow = tokens + row * L_;
  const float4* embv = (const float4*)emb;   // emb row = 64 float4 = 1KB
  float4 a0 = make_float4(0.f, 0.f, 0.f, 0.f);
  float4 a1 = a0, a2 = a0, a3 = a0;
  for (int l0 = half * 64; l0 < len; l0 += 128) {
    int nt = len - l0; nt = nt > 64 ? 64 : nt;
    int tk = (lane < nt) ? trow[l0 + lane] : 0;   // coalesced token load
    int j = 0;
    // 8 independent 1KB row-gathers in flight -> more DRAM bank-level parallelism
    for (; j + 8 <= nt; j += 8) {
      int t0 = __shfl(tk, j);
      int t1 = __shfl(tk, j + 1);
      int t2 = __shfl(tk, j + 2);
      int t3 = __shfl(tk, j + 3);
      int t4 = __shfl(tk, j + 4);
      int t5 = __shfl(tk, j + 5);
      int t6 = __shfl(tk, j + 6);
      int t7 = __shfl(tk, j + 7);
      float4 v0 = embv[(size_t)t0 * 64 + lane];
      float4 v1 = embv[(size_t)t1 * 64 + lane];
      float4 v2 = embv[(size_t)t2 * 64 + lane];
      float4 v3 = embv[(size_t)t3 * 64 + lane];
      float4 v4 = embv[(size_t)t4 * 64 + lane];
      float4 v5 = embv[(size_t)t5 * 64 + lane];
      float4 v6 = embv[(size_t)t6 * 64 + lane];
      float4 v7 = embv[(size_t)t7 * 64 + lane];
      a0.x += v0.x + v4.x; a0.y += v0.y + v4.y; a0.z += v0.z + v4.z; a0.w += v0.w + v4.w;
      a1.x += v1.x + v5.x; a1.y += v1.y + v5.y; a1.z += v1.z + v5.z; a1.w += v1.w + v5.w;
      a2.x += v2.x + v6.x; a2.y += v2.y + v6.y; a2.z += v2.z + v6.z; a2.w += v2.w + v6.w;
      a3.x += v3.x + v7.x; a3.y += v3.y + v7.y; a3.z += v3.z + v7.z; a3.w += v3.w + v7.w;
    }
    for (; j < nt; j++) {
      int t0 = __shfl(tk, j);
      float4 v0 = embv[(size_t)t0 * 64 + lane];
      a0.x += v0.x; a0.y += v0.y; a0.z += v0.z; a0.w += v0.w;
    }
  }
  float4 r;
  r.x = a0.x + a1.x + a2.x + a3.x;
  r.y = a0.y + a1.y + a2.y + a3.y;
  r.z = a0.z + a1.z + a2.z + a3.z;
  r.w = a0.w + a1.w + a2.w + a3.w;
  __shared__ float4 part[2][64];
  if (half) part[wv >> 1][lane] = r;
  __syncthreads();
  if (!half) {
    float4 o = part[wv >> 1][lane];
    const float inv = 1.0f / (float)len;
    r.x = (r.x + o.x) * inv;
    r.y = (r.y + o.y) * inv;
    r.z = (r.z + o.z) * inv;
    r.w = (r.w + o.w) * inv;
    ((float4*)pooled)[(size_t)row * 64 + lane] = r;
  }
}

// ---------------- 2) z = pooled @ W1^T + b1, BN stats accumulated via atomics ----------------
__global__ __launch_bounds__(256) void gemm_stats_kernel(
    const float* __restrict__ pooled, const float* __restrict__ W1p,
    const float* __restrict__ b1, float* __restrict__ z,
    float* __restrict__ ssum, float* __restrict__ ssq) {
  __shared__ float4 SH[1024];   // 16 KB: pooled tile during loop, stats after
  const int tid = threadIdx.x;
  const int b0 = blockIdx.x * 16;
  const float4* pooled4 = (const float4*)pooled;
#pragma unroll
  for (int i = 0; i < 4; i++)
    SH[tid + i * 256] = pooled4[(size_t)b0 * 64 + tid + i * 256];
  __syncthreads();
  const int wv = tid >> 6, lane = tid & 63;
  const int r0 = wv * 4;
  float4 bb = ((const float4*)b1)[lane];
  float acc[4][4];
#pragma unroll
  for (int r = 0; r < 4; r++) {
    acc[r][0] = bb.x; acc[r][1] = bb.y; acc[r][2] = bb.z; acc[r][3] = bb.w;
  }
  const float4* w4 = (const float4*)W1p;
  for (int kb = 0; kb < 64; kb++) {
    float4 wk0 = w4[kb * 256 + lane * 4 + 0];
    float4 wk1 = w4[kb * 256 + lane * 4 + 1];
    float4 wk2 = w4[kb * 256 + lane * 4 + 2];
    float4 wk3 = w4[kb * 256 + lane * 4 + 3];
#pragma unroll
    for (int r = 0; r < 4; r++) {
      float4 p = SH[(r0 + r) * 64 + kb];   // wave-uniform -> LDS broadcast
      acc[r][0] += p.x * wk0.x + p.y * wk0.y + p.z * wk0.z + p.w * wk0.w;
      acc[r][1] += p.x * wk1.x + p.y * wk1.y + p.z * wk1.z + p.w * wk1.w;
      acc[r][2] += p.x * wk2.x + p.y * wk2.y + p.z * wk2.z + p.w * wk2.w;
      acc[r][3] += p.x * wk3.x + p.y * wk3.y + p.z * wk3.z + p.w * wk3.w;
    }
  }
  float4* z4 = (float4*)z;
  float4 s = make_float4(0.f, 0.f, 0.f, 0.f), q = s;
#pragma unroll
  for (int r = 0; r < 4; r++) {
    float4 o = make_float4(acc[r][0], acc[r][1], acc[r][2], acc[r][3]);
    z4[(size_t)(b0 + r0 + r) * 64 + lane] = o;
    s.x += o.x; s.y += o.y; s.z += o.z; s.w += o.w;
    q.x += o.x * o.x; q.y += o.y * o.y; q.z += o.z * o.z; q.w += o.w * o.w;
  }
  __syncthreads();   // done reading pooled tile; reuse SH for stats
  SH[wv * 64 + lane] = s;
  SH[256 + wv * 64 + lane] = q;
  __syncthreads();
  if (tid < 64) {
    float4 S = make_float4(0.f, 0.f, 0.f, 0.f), Q = S;
#pragma unroll
    for (int w = 0; w < 4; w++) {
      float4 a = SH[w * 64 + tid];
      float4 b = SH[256 + w * 64 + tid];
      S.x += a.x; S.y += a.y; S.z += a.z; S.w += a.w;
      Q.x += b.x; Q.y += b.y; Q.z += b.z; Q.w += b.w;
    }
    atomicAdd(&ssum[4 * tid + 0], S.x);
    atomicAdd(&ssum[4 * tid + 1], S.y);
    atomicAdd(&ssum[4 * tid + 2], S.z);
    atomicAdd(&ssum[4 * tid + 3], S.w);
    atomicAdd(&ssq[4 * tid + 0], Q.x);
    atomicAdd(&ssq[4 * tid + 1], Q.y);
    atomicAdd(&ssq[4 * tid + 2], Q.z);
    atomicAdd(&ssq[4 * tid + 3], Q.w);
  }
}

// ---------------- 3) BN finalize + apply + ReLU + dot head + BCE + loss atomic ----------------
__global__ __launch_bounds__(256) void head_loss_kernel(
    const float* __restrict__ z, const float* __restrict__ ssum,
    const float* __restrict__ ssq, const float* __restrict__ gamma,
    const float* __restrict__ beta, const float* __restrict__ w2,
    const float* __restrict__ b2, const float* __restrict__ t,
    float* __restrict__ out) {
  const int tid = threadIdx.x;
  const int wv = tid >> 6, lane = tid & 63;
  const int b = blockIdx.x * 4 + wv;
  float4 s4 = ((const float4*)ssum)[lane];
  float4 q4 = ((const float4*)ssq)[lane];
  float4 g4 = ((const float4*)gamma)[lane];
  float4 be4 = ((const float4*)beta)[lane];
  float4 w24 = ((const float4*)w2)[lane];
  const float invB = 1.0f / 4096.0f;
  float4 A4, C4;
  {
    float m = s4.x * invB, v = q4.x * invB - m * m;
    float rs = rsqrtf(v + 1e-5f); A4.x = g4.x * rs; C4.x = be4.x - m * A4.x;
  }
  {
    float m = s4.y * invB, v = q4.y * invB - m * m;
    float rs = rsqrtf(v + 1e-5f); A4.y = g4.y * rs; C4.y = be4.y - m * A4.y;
  }
  {
    float m = s4.z * invB, v = q4.z * invB - m * m;
    float rs = rsqrtf(v + 1e-5f); A4.z = g4.z * rs; C4.z = be4.z - m * A4.z;
  }
  {
    float m = s4.w * invB, v = q4.w * invB - m * m;
    float rs = rsqrtf(v + 1e-5f); A4.w = g4.w * rs; C4.w = be4.w - m * A4.w;
  }
  float4 zv = ((const float4*)z)[(size_t)b * 64 + lane];
  float h0 = fmaxf(A4.x * zv.x + C4.x, 0.f);
  float h1 = fmaxf(A4.y * zv.y + C4.y, 0.f);
  float h2 = fmaxf(A4.z * zv.z + C4.z, 0.f);
  float h3 = fmaxf(A4.w * zv.w + C4.w, 0.f);
  float part = h0 * w24.x + h1 * w24.y + h2 * w24.z + h3 * w24.w;
#pragma unroll
  for (int off = 32; off > 0; off >>= 1) part += __shfl_down(part, off);
  __shared__ float red[4];
  if (lane == 0) {
    float logit = part + b2[0];
    out[1 + b] = logit;
    float tb = t[b];
    red[wv] = fmaxf(logit, 0.f) - logit * tb + log1pf(expf(-fabsf(logit)));
  }
  __syncthreads();
  if (tid == 0)
    atomicAdd(out, (red[0] + red[1] + red[2] + red[3]) * (1.0f / 4096.0f));
}

extern "C" void kernel_launch(void* const* d_in, const int* in_sizes, int n_in,
                              void* d_out, int out_size, void* d_ws, size_t ws_size,
                              hipStream_t stream) {
  const int* tokens = (const int*)d_in[0];
  const int* lengths = (const int*)d_in[1];
  const float* t = (const float*)d_in[2];
  const float* emb = (const float*)d_in[3];
  const float* W1 = (const float*)d_in[4];
  const float* b1 = (const float*)d_in[5];
  const float* gamma = (const float*)d_in[6];
  const float* beta = (const float*)d_in[7];
  const float* w2 = (const float*)d_in[8];
  const float* b2 = (const float*)d_in[9];
  float* out = (float*)d_out;

  float* wsf = (float*)d_ws;
  float* pooled = wsf;                 // 1,048,576 floats
  float* z = wsf + 1048576;            // 1,048,576
  float* W1p = wsf + 2097152;          // 65,536
  float* ssum = wsf + 2162688;         // 256
  float* ssq = wsf + 2162944;          // 256
  // total ~8.7 MiB of d_ws

  pool_pack_kernel<<<2048, 256, 0, stream>>>(tokens, lengths, emb, pooled,
                                             W1, W1p, ssum, ssq, out);
  gemm_stats_kernel<<<256, 256, 0, stream>>>(pooled, W1p, b1, z, ssum, ssq);
  head_loss_kernel<<<1024, 256, 0, stream>>>(z, ssum, ssq, gamma, beta, w2, b2, t, out);
}